// Round 4
// baseline (915.875 us; speedup 1.0000x reference)
//
#include <hip/hip_runtime.h>

#define DEV __device__ __forceinline__

using short8  = __attribute__((ext_vector_type(8))) short;
using floatx4 = __attribute__((ext_vector_type(4))) float;

DEV unsigned short f2bf(float f) {
  unsigned int u = __float_as_uint(f);
  u += 0x7FFFu + ((u >> 16) & 1u);
  return (unsigned short)(u >> 16);
}
DEV float bf2f(unsigned short u) { return __uint_as_float(((unsigned int)u) << 16); }

DEV void stage16(void* lds, const void* g) {
  __builtin_amdgcn_global_load_lds(
      (__attribute__((address_space(1))) void*)g,
      (__attribute__((address_space(3))) void*)lds, 16, 0, 0);
}

DEV float wave_sum(float x) {
#pragma unroll
  for (int m = 32; m; m >>= 1) x += __shfl_xor(x, m);
  return x;
}
DEV float wave_max(float x) {
#pragma unroll
  for (int m = 32; m; m >>= 1) x = fmaxf(x, __shfl_xor(x, m));
  return x;
}

// ---------------------------------------------------------------------------
// 8-phase 256x256 GEMM core (m201 template port): C = A (MxK) * Bt^T (Bt NxK).
// BK=64, 8 waves (2M x 4N, per-wave 128x64 output), LDS 128 KB = 2 buffers x
// (A 32KB + B 32KB). Even K-tiles -> buf0, odd -> buf1.
// Per iteration (2 K-tiles, 8 phases), each phase:
//   {ds_read subtile -> stage 1 half-tile (2 x global_load_lds) -> barrier ->
//    lgkmcnt(0)+sched_barrier -> setprio(1) 16 MFMA setprio(0) ->
//    [vmcnt(2) at phases 4,8] -> barrier+sched_barrier}
// Stage ledger (iteration i, kt2=2i; reads: PH1-4 buf0=tile kt2, PH5-8 buf1=kt2+1):
//   PH1:Bhi(kt2+1) PH2:Alo(kt2+1) PH3:Ahi(kt2+1) PH4:Blo(kt2+2)
//   PH5:Bhi(kt2+2) PH6:Alo(kt2+2) PH7:Ahi(kt2+2) PH8:Blo(kt2+3)
// Each staged region's last read is >=1 barrier before the stage issue
// (B of buf read at PH1/PH3 (kc0/kc1); A fully read after PH4/PH8).
// vmcnt(2) @PH4 leaves only PH4's 2 loads outstanding -> tile kt2+1 landed
// before PH5 reads; @PH8 -> tile kt2+2 landed before next-iter PH1.
// Final iteration uses vmcnt(0) (no trailing jobs).
// LDS micro-layout (r3-proven, 0 bank conflicts): 16-row x 32-short subtiles
// (1KB), 16B slot c holds global k-chunk c ^ 2*((row>>3)&1); DMA dest linear.
// ---------------------------------------------------------------------------
extern __shared__ char smem[];

#define MFB(va, vb, vc) __builtin_amdgcn_mfma_f32_16x16x32_bf16(va, vb, vc, 0, 0, 0)
#define LD8(boff) (*(const short8*)(smem + (boff)))

#define RDB(KC, BUF)                                   \
  b0 = LD8((BUF) + bof + 0 * 2048 + (KC) * 1024);      \
  b1 = LD8((BUF) + bof + 1 * 2048 + (KC) * 1024);      \
  b2 = LD8((BUF) + bof + 2 * 2048 + (KC) * 1024);      \
  b3 = LD8((BUF) + bof + 3 * 2048 + (KC) * 1024);

#define RDA(FB, KC, BUF)                                     \
  a0 = LD8((BUF) + aof + ((FB) + 0) * 2048 + (KC) * 1024);   \
  a1 = LD8((BUF) + aof + ((FB) + 1) * 2048 + (KC) * 1024);   \
  a2 = LD8((BUF) + aof + ((FB) + 2) * 2048 + (KC) * 1024);   \
  a3 = LD8((BUF) + aof + ((FB) + 3) * 2048 + (KC) * 1024);

#define STG(CLS, MT)                                                         \
  do { const int m_ = (MT);                                                  \
    if (m_ >= 2 && m_ < NT2) {                                               \
      const short* rp_ = ((CLS) & 2) ? (((CLS) & 1) ? rpAhi : rpAlo)         \
                                     : (((CLS) & 1) ? rpBhi : rpBlo);        \
      rp_ += (size_t)m_ * 64;                                                \
      char* d_ = lds_st + ((m_ & 1) << 16) + (((CLS) & 2) ? 0 : 32768)       \
                 + (((CLS) & 1) ? 16384 : 0);                                \
      stage16(d_, rp_);                                                      \
      stage16(d_ + 1024, rp_ + 32);                                          \
    } } while (0)

#define MM(FB)                                                                                 \
  acc[(FB)+0][0] = MFB(a0, b0, acc[(FB)+0][0]); acc[(FB)+0][1] = MFB(a0, b1, acc[(FB)+0][1]);  \
  acc[(FB)+0][2] = MFB(a0, b2, acc[(FB)+0][2]); acc[(FB)+0][3] = MFB(a0, b3, acc[(FB)+0][3]);  \
  acc[(FB)+1][0] = MFB(a1, b0, acc[(FB)+1][0]); acc[(FB)+1][1] = MFB(a1, b1, acc[(FB)+1][1]);  \
  acc[(FB)+1][2] = MFB(a1, b2, acc[(FB)+1][2]); acc[(FB)+1][3] = MFB(a1, b3, acc[(FB)+1][3]);  \
  acc[(FB)+2][0] = MFB(a2, b0, acc[(FB)+2][0]); acc[(FB)+2][1] = MFB(a2, b1, acc[(FB)+2][1]);  \
  acc[(FB)+2][2] = MFB(a2, b2, acc[(FB)+2][2]); acc[(FB)+2][3] = MFB(a2, b3, acc[(FB)+2][3]);  \
  acc[(FB)+3][0] = MFB(a3, b0, acc[(FB)+3][0]); acc[(FB)+3][1] = MFB(a3, b1, acc[(FB)+3][1]);  \
  acc[(FB)+3][2] = MFB(a3, b2, acc[(FB)+3][2]); acc[(FB)+3][3] = MFB(a3, b3, acc[(FB)+3][3]);

#define BARRIER   __builtin_amdgcn_s_barrier()
#define SCHEDB    __builtin_amdgcn_sched_barrier(0)
#define LGKM0     asm volatile("s_waitcnt lgkmcnt(0)" ::: "memory")

#define PHASE_MID(FB)                 \
  BARRIER; LGKM0; SCHEDB;             \
  __builtin_amdgcn_s_setprio(1);      \
  MM(FB);                             \
  __builtin_amdgcn_s_setprio(0);

#define PHASE_END BARRIER; SCHEDB;

DEV void g256_core(const short* __restrict__ A, const short* __restrict__ Bt,
                   const float* __restrict__ bias,
                   float* __restrict__ Cf, unsigned short* __restrict__ Cb,
                   float* __restrict__ C2, int offc2,
                   int N, int K, int m0, int n0) {
  const int tid  = threadIdx.x;
  const int lane = tid & 63;
  const int w    = tid >> 6;       // 0..7
  const int wm   = w >> 2;         // 0..1 : rows wm*128..+127
  const int wn   = w & 3;          // 0..3 : cols wn*64..+63
  const int mr   = lane & 15;
  const int q    = lane >> 4;
  const int NT2  = K >> 6;         // K-tiles of 64 (even: K%128==0)

  // ---- staging geometry (wave w stages subtile rb=w (lo) / 8+w (hi)) ----
  const int srow = lane >> 2;
  const int csw  = ((lane & 3) * 8) ^ (((lane >> 5) & 1) << 4);  // shorts
  const short* rpAlo = A  + (size_t)(m0 + w * 16 + srow) * K + csw;
  const short* rpBlo = Bt + (size_t)(n0 + w * 16 + srow) * K + csw;
  const short* rpAhi = rpAlo + (size_t)128 * K;
  const short* rpBhi = rpBlo + (size_t)128 * K;
  char* lds_st = smem + (w * 2) * 1024 + lane * 16;  // + q2*1024 per load

  // ---- fragment read offsets (bytes) ----
  const int fo  = mr * 64 + ((q * 16) ^ (((mr >> 3) & 1) << 5));
  const int aof = wm * 16384 + fo;           // + fr*2048 + kc*1024 (+buf)
  const int bof = 32768 + wn * 8192 + fo;    // + n*2048 + kc*1024 (+buf)

  floatx4 acc[8][4];
#pragma unroll
  for (int i = 0; i < 8; ++i)
#pragma unroll
    for (int j = 0; j < 4; ++j)
      acc[i][j] = (floatx4){0.f, 0.f, 0.f, 0.f};

  // ---- prologue: stage tiles 0 (first 8 loads) and 1; wait tile 0 ----
#pragma unroll
  for (int mm = 0; mm < 2; ++mm) {
    { char* d = lds_st + (mm << 16) + 32768;         const short* rp = rpBlo + mm * 64; stage16(d, rp); stage16(d + 1024, rp + 32); }
    { char* d = lds_st + (mm << 16) + 32768 + 16384; const short* rp = rpBhi + mm * 64; stage16(d, rp); stage16(d + 1024, rp + 32); }
    { char* d = lds_st + (mm << 16);                 const short* rp = rpAlo + mm * 64; stage16(d, rp); stage16(d + 1024, rp + 32); }
    { char* d = lds_st + (mm << 16) + 16384;         const short* rp = rpAhi + mm * 64; stage16(d, rp); stage16(d + 1024, rp + 32); }
  }
  asm volatile("s_waitcnt vmcnt(8)" ::: "memory");
  BARRIER; SCHEDB;

  short8 a0, a1, a2, a3, b0, b1, b2, b3;

#pragma unroll 1
  for (int kt2 = 0; kt2 < NT2; kt2 += 2) {
    // PH1: rows 0-63 k0 of tile kt2 (buf0)
    RDB(0, 0) RDA(0, 0, 0) STG(1, kt2 + 1);
    PHASE_MID(0) PHASE_END
    // PH2: rows 64-127 k0
    RDA(4, 0, 0) STG(2, kt2 + 1);
    PHASE_MID(4) PHASE_END
    // PH3: rows 0-63 k1
    RDB(1, 0) RDA(0, 1, 0) STG(3, kt2 + 1);
    PHASE_MID(0) PHASE_END
    // PH4: rows 64-127 k1 ; vmcnt checkpoint (tile kt2+1 landed)
    RDA(4, 1, 0) STG(0, kt2 + 2);
    PHASE_MID(4)
    if (kt2 + 2 < NT2) { asm volatile("s_waitcnt vmcnt(2)" ::: "memory"); }
    else               { asm volatile("s_waitcnt vmcnt(0)" ::: "memory"); }
    PHASE_END
    // PH5: rows 0-63 k0 of tile kt2+1 (buf1)
    RDB(0, 65536) RDA(0, 0, 65536) STG(1, kt2 + 2);
    PHASE_MID(0) PHASE_END
    // PH6
    RDA(4, 0, 65536) STG(2, kt2 + 2);
    PHASE_MID(4) PHASE_END
    // PH7
    RDB(1, 65536) RDA(0, 1, 65536) STG(3, kt2 + 2);
    PHASE_MID(0) PHASE_END
    // PH8 ; vmcnt checkpoint (tile kt2+2 landed)
    RDA(4, 1, 65536) STG(0, kt2 + 3);
    PHASE_MID(4)
    if (kt2 + 3 < NT2) { asm volatile("s_waitcnt vmcnt(2)" ::: "memory"); }
    else               { asm volatile("s_waitcnt vmcnt(0)" ::: "memory"); }
    PHASE_END
  }

  // D layout: col=lane&15, row=(lane>>4)*4+reg  [measured m89/m91]
#pragma unroll
  for (int fr = 0; fr < 8; ++fr) {
#pragma unroll
    for (int r = 0; r < 4; ++r) {
      const int row = m0 + wm * 128 + fr * 16 + q * 4 + r;
#pragma unroll
      for (int n = 0; n < 4; ++n) {
        const int col = n0 + wn * 64 + n * 16 + mr;
        float vv = acc[fr][n][r];
        if (bias) vv += bias[col];
        if (Cf) Cf[(size_t)row * N + col] = vv;
        if (Cb) Cb[(size_t)row * N + col] = f2bf(vv);
        if (C2) C2[(size_t)row * 2048 + offc2 + col] = vv;
      }
    }
  }
}

// bijective XCD-aware swizzle of the flattened block id (m204 form)
DEV void xcd_decode(int gx, int gy, int& bx, int& by, int& bz) {
  const int nwg = gx * gy * gridDim.z;
  int bid = ((int)blockIdx.z * gy + (int)blockIdx.y) * gx + (int)blockIdx.x;
  const int qq = nwg >> 3, rr = nwg & 7;
  const int xcd = bid & 7, jj = bid >> 3;
  bid = (xcd < rr ? xcd * (qq + 1) : rr * (qq + 1) + (xcd - rr) * qq) + jj;
  bx = bid % gx;
  const int tmp = bid / gx;
  by = tmp % gy;
  bz = tmp / gy;
}

__global__ __launch_bounds__(512, 2)
void g256_bt(const short* __restrict__ A, long long sAz,
             const short* __restrict__ Bt, long long sBz,
             const float* __restrict__ bias,
             float* __restrict__ Cf, long long sCfz,
             unsigned short* __restrict__ Cb, long long sCbz,
             float* __restrict__ C2, int offc2,
             int N, int K) {
  int bx, by, bz;
  xcd_decode(gridDim.x, gridDim.y, bx, by, bz);
  g256_core(A + (long long)bz * sAz, Bt + (long long)bz * sBz, bias,
            Cf ? Cf + (long long)bz * sCfz : (float*)0,
            Cb ? Cb + (long long)bz * sCbz : (unsigned short*)0,
            C2, offc2, N, K, by * 256, bx * 256);
}

// 5 independent projection jobs in one dispatch (M=8192, N=1024, K=1024 each)
struct ProjJob {
  const short* A;
  const short* Bt;
  const float* bias;
  unsigned short* Cb;
  float* C2;
  long long offc2;
};
struct Proj5 { ProjJob j[5]; };

__global__ __launch_bounds__(512, 2)
void g256_proj5(Proj5 p) {
  int bx, by, bz;
  xcd_decode(gridDim.x, gridDim.y, bx, by, bz);
  ProjJob jb = p.j[0];
#pragma unroll
  for (int i = 1; i < 5; ++i)
    if (bz == i) jb = p.j[i];
  g256_core(jb.A, jb.Bt, jb.bias, (float*)0, jb.Cb, jb.C2, (int)jb.offc2,
            1024, 1024, by * 256, bx * 256);
}

// ---------------------------------------------------------------------------
// Multi-job LayerNorm over D=1024, bf16 in (opt. +f32 bias before stats) -> bf16
// ---------------------------------------------------------------------------
struct LnJob {
  const unsigned short* x;  // ld = 1024
  const float* bias;        // optional, added before stats
  const float* g;
  const float* Bb;
  unsigned short* y;        // ld = 1024
  float scale;
};

__global__ __launch_bounds__(256)
void ln_multi(LnJob j0, LnJob j1, LnJob j2, LnJob j3, LnJob j4) {
  LnJob jb = j0;
  if (blockIdx.y == 1) jb = j1;
  else if (blockIdx.y == 2) jb = j2;
  else if (blockIdx.y == 3) jb = j3;
  else if (blockIdx.y == 4) jb = j4;
  const int row = blockIdx.x, t = threadIdx.x;
  const ushort4 xv = ((const ushort4*)(jb.x + (size_t)row * 1024))[t];
  float4 v = {bf2f(xv.x), bf2f(xv.y), bf2f(xv.z), bf2f(xv.w)};
  if (jb.bias) {
    const float4 b4 = ((const float4*)jb.bias)[t];
    v.x += b4.x; v.y += b4.y; v.z += b4.z; v.w += b4.w;
  }
  float s  = v.x + v.y + v.z + v.w;
  float s2 = v.x * v.x + v.y * v.y + v.z * v.z + v.w * v.w;
  s = wave_sum(s);
  s2 = wave_sum(s2);
  __shared__ float r1[4], r2[4];
  const int w = t >> 6, lane = t & 63;
  if (!lane) { r1[w] = s; r2[w] = s2; }
  __syncthreads();
  s  = r1[0] + r1[1] + r1[2] + r1[3];
  s2 = r2[0] + r2[1] + r2[2] + r2[3];
  const float mean = s * (1.f / 1024.f);
  const float var  = s2 * (1.f / 1024.f) - mean * mean;
  const float rstd = 1.f / sqrtf(var + 1e-6f);
  const float4 g4 = ((const float4*)jb.g)[t];
  const float4 b4 = ((const float4*)jb.Bb)[t];
  ushort4 o;
  o.x = f2bf(((v.x - mean) * rstd * g4.x + b4.x) * jb.scale);
  o.y = f2bf(((v.y - mean) * rstd * g4.y + b4.y) * jb.scale);
  o.z = f2bf(((v.z - mean) * rstd * g4.z + b4.z) * jb.scale);
  o.w = f2bf(((v.w - mean) * rstd * g4.w + b4.w) * jb.scale);
  ((ushort4*)(jb.y + (size_t)row * 1024))[t] = o;
}

// ---------------------------------------------------------------------------
// Row softmax over 2048 f32 -> bf16 P (+ optional f32 a2 copy)
// ---------------------------------------------------------------------------
__global__ __launch_bounds__(256)
void softmax_kernel(const float* __restrict__ S, unsigned short* __restrict__ P,
                    float* __restrict__ A2) {
  const int row = blockIdx.x, t = threadIdx.x;
  const float4* sr = (const float4*)(S + (size_t)row * 2048);
  float4 a = sr[t], b = sr[t + 256];
  float m = fmaxf(fmaxf(fmaxf(a.x, a.y), fmaxf(a.z, a.w)),
                  fmaxf(fmaxf(b.x, b.y), fmaxf(b.z, b.w)));
  m = wave_max(m);
  __shared__ float red[4];
  const int w = t >> 6, lane = t & 63;
  if (!lane) red[w] = m;
  __syncthreads();
  m = fmaxf(fmaxf(red[0], red[1]), fmaxf(red[2], red[3]));
  a.x = __expf(a.x - m); a.y = __expf(a.y - m); a.z = __expf(a.z - m); a.w = __expf(a.w - m);
  b.x = __expf(b.x - m); b.y = __expf(b.y - m); b.z = __expf(b.z - m); b.w = __expf(b.w - m);
  float s = a.x + a.y + a.z + a.w + b.x + b.y + b.z + b.w;
  s = wave_sum(s);
  __syncthreads();
  if (!lane) red[w] = s;
  __syncthreads();
  s = red[0] + red[1] + red[2] + red[3];
  const float inv = 1.f / s;
  a.x *= inv; a.y *= inv; a.z *= inv; a.w *= inv;
  b.x *= inv; b.y *= inv; b.z *= inv; b.w *= inv;
  ushort4 o0, o1;
  o0.x = f2bf(a.x); o0.y = f2bf(a.y); o0.z = f2bf(a.z); o0.w = f2bf(a.w);
  o1.x = f2bf(b.x); o1.y = f2bf(b.y); o1.z = f2bf(b.z); o1.w = f2bf(b.w);
  ((ushort4*)(P + (size_t)row * 2048))[t] = o0;
  ((ushort4*)(P + (size_t)row * 2048))[t + 256] = o1;
  if (A2) {
    float4* ar = (float4*)(A2 + (size_t)row * 2048);
    ar[t] = a;
    ar[t + 256] = b;
  }
}

// ---------------------------------------------------------------------------
__global__ __launch_bounds__(256)
void cast3_kernel(const float* __restrict__ x0, const float* __restrict__ x1,
                  const float* __restrict__ x2, unsigned short* __restrict__ y0,
                  unsigned short* __restrict__ y1, unsigned short* __restrict__ y2) {
  const float* x = blockIdx.y == 0 ? x0 : (blockIdx.y == 1 ? x1 : x2);
  unsigned short* y = blockIdx.y == 0 ? y0 : (blockIdx.y == 1 ? y1 : y2);
  const int i = blockIdx.x * 256 + threadIdx.x;
  const float4 v = ((const float4*)x)[i];
  ushort4 o;
  o.x = f2bf(v.x); o.y = f2bf(v.y); o.z = f2bf(v.z); o.w = f2bf(v.w);
  ((ushort4*)y)[i] = o;
}

struct W8 {
  const float* src[8];
  unsigned short* dst[8];
};

__global__ __launch_bounds__(256)
void transpose_w8_kernel(W8 p) {
  __shared__ unsigned short tile[64][65];
  const float* in = p.src[blockIdx.z];
  unsigned short* out = p.dst[blockIdx.z];
  const int tr0 = blockIdx.y * 64, tc0 = blockIdx.x * 64;
  const int x = threadIdx.x & 63, y = threadIdx.x >> 6;
#pragma unroll
  for (int i = 0; i < 16; ++i) {
    const int r = i * 4 + y;
    tile[r][x] = f2bf(in[(size_t)(tr0 + r) * 1024 + tc0 + x]);
  }
  __syncthreads();
#pragma unroll
  for (int i = 0; i < 16; ++i) {
    const int r = i * 4 + y;
    out[(size_t)(tc0 + r) * 1024 + tr0 + x] = tile[x][r];
  }
}

__global__ __launch_bounds__(256)
void transpose_v8_kernel(const unsigned short* __restrict__ in0,
                         const unsigned short* __restrict__ in1,
                         unsigned short* __restrict__ out0,
                         unsigned short* __restrict__ out1) {
  __shared__ unsigned short tile[64][65];
  const int zz = blockIdx.z & 3;
  const unsigned short* in = (blockIdx.z < 4 ? in0 : in1) + (size_t)zz * 2048 * 1024;
  unsigned short* out = (blockIdx.z < 4 ? out0 : out1) + (size_t)zz * 1024 * 2048;
  const int tr0 = blockIdx.y * 64, tc0 = blockIdx.x * 64;
  const int x = threadIdx.x & 63, y = threadIdx.x >> 6;
#pragma unroll
  for (int i = 0; i < 16; ++i) {
    const int r = i * 4 + y;
    tile[r][x] = in[(size_t)(tr0 + r) * 1024 + tc0 + x];
  }
  __syncthreads();
#pragma unroll
  for (int i = 0; i < 16; ++i) {
    const int r = i * 4 + y;
    out[(size_t)(tc0 + r) * 2048 + tr0 + x] = tile[x][r];
  }
}

// ---------------------------------------------------------------------------
extern "C" void kernel_launch(void* const* d_in, const int* in_sizes, int n_in,
                              void* d_out, int out_size, void* d_ws, size_t ws_size,
                              hipStream_t stream) {
  const float* q = (const float*)d_in[0];
  const float* k = (const float*)d_in[1];
  const float* v = (const float*)d_in[2];
  const float* W[8];
  const float* bW[8];
  for (int i = 0; i < 8; ++i) {
    W[i]  = (const float*)d_in[3 + 2 * i];
    bW[i] = (const float*)d_in[4 + 2 * i];
  }
  const float* g_[6];
  const float* B_[6];
  for (int i = 0; i < 6; ++i) {
    g_[i] = (const float*)d_in[19 + 2 * i];
    B_[i] = (const float*)d_in[20 + 2 * i];
  }

  // allow 128 KB dynamic LDS for the GEMM kernels (idempotent host calls)
  static bool attr_done = false;
  if (!attr_done) {
    hipFuncSetAttribute((const void*)g256_bt,
                        hipFuncAttributeMaxDynamicSharedMemorySize, 131072);
    hipFuncSetAttribute((const void*)g256_proj5,
                        hipFuncAttributeMaxDynamicSharedMemorySize, 131072);
    attr_done = true;
  }

  float* out_p = (float*)d_out;          // (4,2048,1024)
  float* res_p = out_p + 8388608;        // (8192,2048)
  float* a2_p  = res_p + 16777216;       // (4,2048,2048)

  // workspace layout (~338 MB)
  char* ws = (char*)d_ws;
  const size_t MBy = 1u << 20;
  unsigned short* WT   = (unsigned short*)ws;                 // 8 x 2MB
  unsigned short* qb   = (unsigned short*)(ws + 16 * MBy);
  unsigned short* kb   = (unsigned short*)(ws + 32 * MBy);
  unsigned short* vb   = (unsigned short*)(ws + 48 * MBy);
  unsigned short* pb   = (unsigned short*)(ws + 64 * MBy);    // 5 x 16MB proj slices
  float* Sbuf          = (float*)(ws + 64 * MBy);             // 67MB, aliases pb (dead after LN)
  unsigned short* lnq  = (unsigned short*)(ws + 144 * MBy);
  unsigned short* lnk1 = (unsigned short*)(ws + 160 * MBy);
  unsigned short* lnk2 = (unsigned short*)(ws + 176 * MBy);
  unsigned short* lnv1 = (unsigned short*)(ws + 192 * MBy);
  unsigned short* lnv2 = (unsigned short*)(ws + 208 * MBy);
  unsigned short* lnvT1= (unsigned short*)(ws + 224 * MBy);
  unsigned short* lnvT2= (unsigned short*)(ws + 240 * MBy);
  unsigned short* P    = (unsigned short*)(ws + 256 * MBy);   // 33MB
  unsigned short* ofb  = (unsigned short*)(ws + 290 * MBy);
  unsigned short* ob   = (unsigned short*)(ws + 306 * MBy);
  unsigned short* qf2b = (unsigned short*)(ws + 322 * MBy);

  const size_t SL = 8192ull * 1024;  // proj slice elements

  auto gemm = [&](const unsigned short* A, long long sAz,
                  const unsigned short* Bt, long long sBz, const float* bias,
                  float* Cf, long long sCfz, unsigned short* Cb, long long sCbz,
                  float* C2, int offc2, int M, int N, int K, int Z) {
    dim3 grid(N / 256, M / 256, Z);
    g256_bt<<<grid, 512, 131072, stream>>>((const short*)A, sAz, (const short*)Bt, sBz,
                                           bias, Cf, sCfz, Cb, sCbz, C2, offc2, N, K);
  };
  LnJob nil{};

  // ---- prep ----
  cast3_kernel<<<dim3(8192, 3), 256, 0, stream>>>(q, k, v, qb, kb, vb);
  W8 w8;
  for (int i = 0; i < 8; ++i) { w8.src[i] = W[i]; w8.dst[i] = WT + (size_t)i * 1048576; }
  transpose_w8_kernel<<<dim3(16, 16, 8), 256, 0, stream>>>(w8);

  // ---- all 5 projections in one dispatch (k1,k2,v1,v2,q1) ----
  {
    Proj5 p;
    p.j[0] = {(const short*)kb, (const short*)(WT + 1u * 1048576), 0, pb + 0 * SL, 0, 0};
    p.j[1] = {(const short*)kb, (const short*)(WT + 5u * 1048576), 0, pb + 1 * SL, 0, 0};
    p.j[2] = {(const short*)vb, (const short*)(WT + 2u * 1048576), 0, pb + 2 * SL, 0, 0};
    p.j[3] = {(const short*)vb, (const short*)(WT + 6u * 1048576), 0, pb + 3 * SL, 0, 0};
    p.j[4] = {(const short*)qb, (const short*)(WT + 0u * 1048576), bW[0], pb + 4 * SL, res_p, 0};
    g256_proj5<<<dim3(4, 32, 5), 512, 131072, stream>>>(p);
  }

  // ---- all 5 first-phase LayerNorms in one dispatch ----
  {
    LnJob jk1{pb + 0 * SL, bW[1], g_[1], B_[1], lnk1, 1.f};
    LnJob jk2{pb + 1 * SL, bW[5], g_[4], B_[4], lnk2, 1.f};
    LnJob jv1{pb + 2 * SL, bW[2], g_[2], B_[2], lnv1, 1.f};
    LnJob jv2{pb + 3 * SL, bW[6], g_[5], B_[5], lnv2, 1.f};
    LnJob jq1{pb + 4 * SL, 0,     g_[0], B_[0], lnq,  1.f / 32.f};
    ln_multi<<<dim3(8192, 5), 256, 0, stream>>>(jk1, jk2, jv1, jv2, jq1);
  }
  transpose_v8_kernel<<<dim3(16, 32, 8), 256, 0, stream>>>(lnv1, lnv2, lnvT1, lnvT2);

  // ---- layer 1 attention ----
  gemm(lnq, 2048ll * 1024, lnk1, 2048ll * 1024, 0, Sbuf, 2048ll * 2048, 0, 0, 0, 0,
       2048, 2048, 1024, 4);
  softmax_kernel<<<8192, 256, 0, stream>>>(Sbuf, P, (float*)0);
  gemm(P, 2048ll * 2048, lnvT1, 1024ll * 2048, 0, 0, 0, ob, 2048ll * 1024, 0, 0,
       2048, 1024, 2048, 4);
  gemm(ob, 0, WT + 3u * 1048576, 0, bW[3], 0, 0, ofb, 0, 0, 0, 8192, 1024, 1024, 1);

  // ---- layer 2 ----
  gemm(ofb, 0, WT + 4u * 1048576, 0, bW[4], 0, 0, qf2b, 0, res_p, 1024, 8192, 1024, 1024, 1);
  {
    LnJob jq2{qf2b, 0, g_[3], B_[3], lnq, 1.f / 32.f};
    ln_multi<<<dim3(8192, 1), 256, 0, stream>>>(jq2, nil, nil, nil, nil);
  }
  gemm(lnq, 2048ll * 1024, lnk2, 2048ll * 1024, 0, Sbuf, 2048ll * 2048, 0, 0, 0, 0,
       2048, 2048, 1024, 4);
  softmax_kernel<<<8192, 256, 0, stream>>>(Sbuf, P, a2_p);
  gemm(P, 2048ll * 2048, lnvT2, 1024ll * 2048, 0, 0, 0, ob, 2048ll * 1024, 0, 0,
       2048, 1024, 2048, 4);
  gemm(ob, 0, WT + 7u * 1048576, 0, bW[7], out_p, 0, 0, 0, 0, 0, 8192, 1024, 1024, 1);
}